// Round 1
// baseline (939.002 us; speedup 1.0000x reference)
//
#include <hip/hip_runtime.h>

// UniformShardedEmbeddingBags: B=1024, T=32, D=64, E=100000, L=50
// bag b in [0, B*T): t = b % T; out[b, :] = sum_{n in [off[b], off[b+1])} W[idx[n], t, :]
//
// One 64-lane wave per bag. Lane decomposition: r = lane>>4 (row-slot 0..3),
// c = lane&15 (float4 column). One global_load_dwordx4 fetches FOUR whole
// 256B rows per wave (16B/lane coalescing sweet spot) -> 13 loads cover 50 rows.
// Indices are preloaded once per bag (coalesced) and broadcast via __shfl, so
// the gather loads have no dependent feature-load in front of them -> all can
// be in flight together (latency was the bottleneck, not bandwidth).
// Bag remap clusters concurrent waves onto the same t-slice so the live
// working set (~8 x 25.6MB) is L3-resident and repeat rows hit cache.

constexpr int kT = 32;
constexpr int kD = 64;
constexpr int kL = 50;   // rows per bag in this problem (runtime-checked)

__global__ __launch_bounds__(256) void embag_kernel(
    const float* __restrict__ weights,   // (E, T, D)
    const int*   __restrict__ features,  // (N,)
    const int*   __restrict__ offsets,   // (num_bags+1,)
    float*       __restrict__ out,       // (num_bags, D)
    int num_bags)
{
    const int gwave = (int)((blockIdx.x * 256u + threadIdx.x) >> 6);
    const int lane  = (int)(threadIdx.x & 63u);
    if (gwave >= num_bags) return;

    // t-locality remap: consecutive waves share t = bag % 32, so the
    // concurrently-resident gather working set is a few 25.6MB t-slices
    // (L3-resident) instead of the full 819MB table. Bijective when
    // num_bags % 32 == 0; falls back to identity otherwise.
    int bag = gwave;
    if ((num_bags & (kT - 1)) == 0) {
        const int groups = num_bags >> 5;            // bags per t (1024 here)
        bag = (gwave % groups) * kT + (gwave / groups);
    }

    const int t     = bag & (kT - 1);                // bag % T (T == 32)
    const int start = offsets[bag];
    const int end   = offsets[bag + 1];
    const int count = end - start;

    const int r = lane >> 4;                         // row slot 0..3
    const int c = lane & 15;                         // float4 column 0..15

    const float*  wbase      = weights + (size_t)t * kD + (size_t)(c * 4);
    const size_t  row_stride = (size_t)kT * kD;      // 2048 floats per e-step

    float4 acc0 = make_float4(0.f, 0.f, 0.f, 0.f);
    float4 acc1 = make_float4(0.f, 0.f, 0.f, 0.f);

    if (count == kL) {
        // Preload all 50 indices: lane i holds features[start+i] (clamped).
        const int idx = features[start + (lane < kL ? lane : kL - 1)];

        // 13 wave-loads x 4 rows = 52 row slots; last two are masked.
        #pragma unroll
        for (int k = 0; k < 13; ++k) {
            const int row = k * 4 + r;
            const int e   = __shfl(idx, row < kL ? row : (kL - 1), 64);
            const float4 v = *(const float4*)(wbase + (size_t)e * row_stride);
            const float  s = (row < kL) ? 1.0f : 0.0f;   // folds to add for k<12
            if (k & 1) {
                acc1.x = fmaf(v.x, s, acc1.x);
                acc1.y = fmaf(v.y, s, acc1.y);
                acc1.z = fmaf(v.z, s, acc1.z);
                acc1.w = fmaf(v.w, s, acc1.w);
            } else {
                acc0.x = fmaf(v.x, s, acc0.x);
                acc0.y = fmaf(v.y, s, acc0.y);
                acc0.z = fmaf(v.z, s, acc0.z);
                acc0.w = fmaf(v.w, s, acc0.w);
            }
        }
    } else {
        // Generic fallback: row slots stride over the bag; correct for any count.
        for (int n = start + r; n < end; n += 4) {
            const int e = features[n];
            const float4 v = *(const float4*)(wbase + (size_t)e * row_stride);
            acc0.x += v.x; acc0.y += v.y; acc0.z += v.z; acc0.w += v.w;
        }
    }

    float4 acc = make_float4(acc0.x + acc1.x, acc0.y + acc1.y,
                             acc0.z + acc1.z, acc0.w + acc1.w);

    // Reduce across the 4 row-slot groups (lanes differing in bits 4..5).
    acc.x += __shfl_xor(acc.x, 16, 64);
    acc.y += __shfl_xor(acc.y, 16, 64);
    acc.z += __shfl_xor(acc.z, 16, 64);
    acc.w += __shfl_xor(acc.w, 16, 64);
    acc.x += __shfl_xor(acc.x, 32, 64);
    acc.y += __shfl_xor(acc.y, 32, 64);
    acc.z += __shfl_xor(acc.z, 32, 64);
    acc.w += __shfl_xor(acc.w, 32, 64);

    if (r == 0) {
        *(float4*)(out + (size_t)bag * kD + (size_t)(c * 4)) = acc;
    }
}

extern "C" void kernel_launch(void* const* d_in, const int* in_sizes, int n_in,
                              void* d_out, int out_size, void* d_ws, size_t ws_size,
                              hipStream_t stream) {
    const float* weights  = (const float*)d_in[0];
    const int*   features = (const int*)d_in[1];
    const int*   offsets  = (const int*)d_in[2];
    float*       out      = (float*)d_out;

    const int num_bags = in_sizes[2] - 1;       // B*T
    const int threads  = 256;                   // 4 waves -> 4 bags per block
    const int waves    = num_bags;
    const int blocks   = (waves * 64 + threads - 1) / threads;

    embag_kernel<<<blocks, threads, 0, stream>>>(weights, features, offsets, out, num_bags);
}